// Round 9
// baseline (626.166 us; speedup 1.0000x reference)
//
#include <hip/hip_runtime.h>
#include <hip/hip_bf16.h>
#include <hip/hip_fp16.h>
#include <cstdint>

#define IND 128
#define HID 64
#define NEG_SLOPE 0.2f
#define KSPL 64       // K split for proj staging
#define PSTR 68       // 64 + 4: 16B-aligned LDS rows, bank offset 4/row
#define EPB 4096      // edges per sort block
#define CBSHIFT 8     // coarse bucket = 256 consecutive dst nodes

__device__ __forceinline__ unsigned short f2bf_bits(float f) {
  __hip_bfloat16 b = __float2bfloat16(f);
  return *reinterpret_cast<unsigned short*>(&b);
}
__device__ __forceinline__ unsigned short f2h_bits(float f) {
  __half h = __float2half(f);
  return *reinterpret_cast<unsigned short*>(&h);
}
__device__ __forceinline__ float h2f_bits(unsigned short u) {
  __half_raw r; r.x = u;
  return __half2float(__half(r));
}

// ---------------------------------------------------------------------------
// K1: h(bf16) = x @ W.T ; a_src = h @ att_src ; a_dst = h @ att_dst (fp32).
// Tiled GEMM 64x64, K staged in two 64-wide halves (LDS 34.8KB -> 4 blk/CU).
// Microtile 4x4, fp32 accumulate; h stored bf16 (ushort4 per thread/node).
// ---------------------------------------------------------------------------
__global__ __launch_bounds__(256) void k_proj(
    const float* __restrict__ x, const float* __restrict__ W,
    const float* __restrict__ att_s, const float* __restrict__ att_d,
    unsigned short* __restrict__ h, float* __restrict__ a_src,
    float* __restrict__ a_dst, int n)
{
  __shared__ float xs[64 * PSTR];
  __shared__ float wt[64 * PSTR];
  __shared__ float sa_l[64], sd_l[64];

  const int tid = threadIdx.x;
  const int nodeBase = blockIdx.x * 64;
  if (tid < 64) { sa_l[tid] = 0.f; sd_l[tid] = 0.f; }

  const int ng = tid & 15;   // node group (4 nodes)
  const int hg = tid >> 4;   // hid group (4 dims)

  float acc[4][4];
#pragma unroll
  for (int j = 0; j < 4; ++j)
#pragma unroll
    for (int i = 0; i < 4; ++i) acc[j][i] = 0.f;

  for (int kb = 0; kb < IND; kb += KSPL) {
    __syncthreads();   // protect LDS from previous half's compute
#pragma unroll
    for (int it = 0; it < 4; ++it) {
      int fi = (it * 256 + tid) * 4;      // 0..4095 floats of this half
      int r = fi >> 6, k = fi & 63;
      float4 wv = *(const float4*)(W + (size_t)r * IND + kb + k);
      *(float4*)&wt[r * PSTR + k] = wv;
      int node = nodeBase + r; if (node >= n) node = n - 1;
      float4 xv = *(const float4*)(x + (size_t)node * IND + kb + k);
      *(float4*)&xs[r * PSTR + k] = xv;
    }
    __syncthreads();

    const float* xrow0 = &xs[(4 * ng) * PSTR];
    const float* wrow0 = &wt[(4 * hg) * PSTR];
    for (int k = 0; k < KSPL; k += 4) {
      float4 a[4], b[4];
#pragma unroll
      for (int j = 0; j < 4; ++j) a[j] = *(const float4*)(xrow0 + j * PSTR + k);
#pragma unroll
      for (int i = 0; i < 4; ++i) b[i] = *(const float4*)(wrow0 + i * PSTR + k);
#pragma unroll
      for (int j = 0; j < 4; ++j)
#pragma unroll
        for (int i = 0; i < 4; ++i) {
          acc[j][i] = fmaf(a[j].x, b[i].x, acc[j][i]);
          acc[j][i] = fmaf(a[j].y, b[i].y, acc[j][i]);
          acc[j][i] = fmaf(a[j].z, b[i].z, acc[j][i]);
          acc[j][i] = fmaf(a[j].w, b[i].w, acc[j][i]);
        }
    }
  }

  // h tile store (bf16): 4 dims = 8B per (thread, node)
#pragma unroll
  for (int j = 0; j < 4; ++j) {
    int node = nodeBase + 4 * ng + j;
    if (node < n) {
      ushort4 hv;
      hv.x = f2bf_bits(acc[j][0]);
      hv.y = f2bf_bits(acc[j][1]);
      hv.z = f2bf_bits(acc[j][2]);
      hv.w = f2bf_bits(acc[j][3]);
      *(ushort4*)(h + (size_t)node * HID + 4 * hg) = hv;
    }
  }

  // fused a_src/a_dst in fp32 (scores stay full precision)
  float4 as4 = *(const float4*)(att_s + 4 * hg);
  float4 ad4 = *(const float4*)(att_d + 4 * hg);
#pragma unroll
  for (int j = 0; j < 4; ++j) {
    float ps = acc[j][0]*as4.x + acc[j][1]*as4.y + acc[j][2]*as4.z + acc[j][3]*as4.w;
    float pd = acc[j][0]*ad4.x + acc[j][1]*ad4.y + acc[j][2]*ad4.z + acc[j][3]*ad4.w;
    ps += __shfl_xor(ps, 16, 64); ps += __shfl_xor(ps, 32, 64);
    pd += __shfl_xor(pd, 16, 64); pd += __shfl_xor(pd, 32, 64);
    if ((tid & 63) < 16) {
      atomicAdd(&sa_l[4 * ng + j], ps);
      atomicAdd(&sd_l[4 * ng + j], pd);
    }
  }
  __syncthreads();
  if (tid < 64) {
    int node = nodeBase + tid;
    if (node < n) { a_src[node] = sa_l[tid]; a_dst[node] = sd_l[tid]; }
  }
}

// ---------------------------------------------------------------------------
// K2: per-(sort block, coarse bucket) histogram. cnt bucket-major.
// ---------------------------------------------------------------------------
__global__ __launch_bounds__(256) void k_cnt(
    const int* __restrict__ ei, int* __restrict__ cnt,
    int E, long long E2, int nblk, int nbuck)
{
  __shared__ int hist[256];
  const int tid = threadIdx.x;
  hist[tid] = 0;
  __syncthreads();

  const long long i0 = (long long)blockIdx.x * EPB;
  const int cntE = (int)((E2 - i0 < EPB) ? (E2 - i0) : EPB);
  for (int j = tid; j < cntE; j += 256) {
    long long idx = i0 + j;
    int d = (idx < E) ? ei[E + idx] : (int)(idx - E);
    atomicAdd(&hist[d >> CBSHIFT], 1);
  }
  __syncthreads();
  if (tid < nbuck) cnt[tid * nblk + blockIdx.x] = hist[tid];
}

// ---------------------------------------------------------------------------
// K3a/b/c: multi-block exclusive scan of cnt[0..cntN) -> cntS.
// ---------------------------------------------------------------------------
__global__ __launch_bounds__(256) void k_scan_a(
    const int* __restrict__ vals, int* __restrict__ blockSums, int cntN)
{
  __shared__ int red[4];
  int i = blockIdx.x * 256 + threadIdx.x;
  int v = (i < cntN) ? vals[i] : 0;
#pragma unroll
  for (int o = 32; o; o >>= 1) v += __shfl_xor(v, o, 64);
  if ((threadIdx.x & 63) == 0) red[threadIdx.x >> 6] = v;
  __syncthreads();
  if (threadIdx.x == 0)
    blockSums[blockIdx.x] = red[0] + red[1] + red[2] + red[3];
}

__global__ __launch_bounds__(1024) void k_scan_b(
    int* __restrict__ blockSums, int nb)
{
  __shared__ int sums[1024];
  const int tid = threadIdx.x;
  int v = (tid < nb) ? blockSums[tid] : 0;
  sums[tid] = v;
  __syncthreads();
  for (int off = 1; off < 1024; off <<= 1) {
    int t = (tid >= off) ? sums[tid - off] : 0;
    __syncthreads();
    sums[tid] += t;
    __syncthreads();
  }
  if (tid < nb) blockSums[tid] = sums[tid] - v;
}

__global__ __launch_bounds__(256) void k_scan_c(
    const int* __restrict__ vals, const int* __restrict__ blockSums,
    int* __restrict__ out, int cntN)
{
  __shared__ int sums[256];
  const int tid = threadIdx.x;
  int i = blockIdx.x * 256 + tid;
  int v = (i < cntN) ? vals[i] : 0;
  sums[tid] = v;
  __syncthreads();
  for (int off = 1; off < 256; off <<= 1) {
    int t = (tid >= off) ? sums[tid - off] : 0;
    __syncthreads();
    sums[tid] += t;
    __syncthreads();
  }
  if (i < cntN) out[i] = sums[tid] - v + blockSums[blockIdx.x];
}

// ---------------------------------------------------------------------------
// K4: block-level counting sort of EPB edges by coarse bucket, then LINEAR
// write-out (block owns each run -> lines fill). Packed 4B: (dst<<16)|src.
// ---------------------------------------------------------------------------
__global__ __launch_bounds__(256) void k_sortout(
    const int* __restrict__ ei, const int* __restrict__ cntS,
    unsigned* __restrict__ tmp, int E, long long E2, int nblk, int nbuck)
{
  __shared__ int hist[256];
  __shared__ int sums[256];
  __shared__ int cur[256];
  __shared__ int gbase[256];
  __shared__ unsigned sorted[EPB];

  const int tid = threadIdx.x;
  hist[tid] = 0;
  __syncthreads();

  const long long i0 = (long long)blockIdx.x * EPB;

  unsigned pk[EPB / 256];
#pragma unroll
  for (int j = 0; j < EPB / 256; ++j) {
    long long idx = i0 + j * 256 + tid;
    unsigned v = 0xFFFFFFFFu;
    if (idx < E2) {
      int s, d;
      if (idx < E) { s = ei[idx]; d = ei[E + idx]; }
      else         { s = d = (int)(idx - E); }
      v = ((unsigned)d << 16) | (unsigned)s;
      atomicAdd(&hist[d >> CBSHIFT], 1);
    }
    pk[j] = v;
  }
  __syncthreads();

  sums[tid] = hist[tid];
  __syncthreads();
  for (int off = 1; off < 256; off <<= 1) {
    int t = (tid >= off) ? sums[tid - off] : 0;
    __syncthreads();
    sums[tid] += t;
    __syncthreads();
  }
  const int lstart_t = sums[tid] - hist[tid];
  cur[tid] = lstart_t;
  gbase[tid] = (tid < nbuck) ? cntS[tid * nblk + blockIdx.x] : 0;
  __syncthreads();
  hist[tid] = lstart_t;
  __syncthreads();

#pragma unroll
  for (int j = 0; j < EPB / 256; ++j) {
    unsigned v = pk[j];
    if (v != 0xFFFFFFFFu) {
      int b = v >> (16 + CBSHIFT);
      int lpos = atomicAdd(&cur[b], 1);
      sorted[lpos] = v;
    }
  }
  __syncthreads();

  const int cntE = (int)((E2 - i0 < EPB) ? (E2 - i0) : EPB);
  for (int i = tid; i < cntE; i += 256) {
    unsigned v = sorted[i];
    int b = v >> (16 + CBSHIFT);
    tmp[gbase[b] + (i - hist[b])] = v;
  }
}

// ---------------------------------------------------------------------------
// K5: per-coarse-bucket exact CSR + edge weight. Block owns the bucket's
// contiguous CSR region: LDS deg -> scan -> row_start, LDS int cursors ->
// csr4 packed {src:16, fp16(w):16} (4B/edge, block-owned dense writes).
// ---------------------------------------------------------------------------
__global__ __launch_bounds__(256) void k_csr(
    const unsigned* __restrict__ tmp, const int* __restrict__ cntS,
    const float* __restrict__ a_src, const float* __restrict__ a_dst,
    int* __restrict__ row_start, unsigned* __restrict__ csr4,
    int E2total, int n, int nblk, int nbuck)
{
  __shared__ int degl[256], sums[256], cur[256];
  __shared__ float adl[256];

  const int tid = threadIdx.x;
  const int b   = blockIdx.x;
  const int n0  = b << CBSHIFT;
  const int base = cntS[b * nblk];
  const int next = (b + 1 < nbuck) ? cntS[(b + 1) * nblk] : E2total;

  degl[tid] = 0;
  const int node = n0 + tid;
  adl[tid] = (node < n) ? a_dst[node] : 0.f;
  __syncthreads();

  for (int i = base + tid; i < next; i += 256)
    atomicAdd(&degl[(tmp[i] >> 16) - n0], 1);
  __syncthreads();

  sums[tid] = degl[tid];
  __syncthreads();
  for (int off = 1; off < 256; off <<= 1) {
    int t = (tid >= off) ? sums[tid - off] : 0;
    __syncthreads();
    sums[tid] += t;
    __syncthreads();
  }
  const int rs = base + sums[tid] - degl[tid];
  cur[tid] = rs;
  if (node < n) row_start[node] = rs;
  if (b == nbuck - 1 && tid == 0) row_start[n] = E2total;
  __syncthreads();

  for (int i = base + tid; i < next; i += 256) {
    unsigned v = tmp[i];
    int s  = (int)(v & 0xFFFFu);
    int dl = (int)(v >> 16) - n0;
    float sc = a_src[s] + adl[dl];
    sc = (sc >= 0.f) ? sc : NEG_SLOPE * sc;
    float w = expf(sc);
    int pos = atomicAdd(&cur[dl], 1);
    csr4[pos] = (unsigned)s | ((unsigned)f2h_bits(w) << 16);
  }
}

// ---------------------------------------------------------------------------
// K6: single-pass gather + epilogue. One wave per node. csr4 read once:
// w-sum accumulates in-register alongside the aggregate. Two edges per wave
// iteration: lanes 0-31 handle edge j (dims via bf16x2), lanes 32-63 edge
// j+1; halves combined with one shfl_xor(32) at the end. Register acc only.
// ---------------------------------------------------------------------------
__global__ __launch_bounds__(256) void k_gather_final(
    const int* __restrict__ row_start, const unsigned* __restrict__ csr4,
    const unsigned* __restrict__ h2, const float* __restrict__ bias,
    const float* __restrict__ W_lin, const float* __restrict__ b_lin,
    float* __restrict__ y, int n)
{
  const int lane = threadIdx.x & 63;
  const int wid  = threadIdx.x >> 6;
  const int node = blockIdx.x * 4 + wid;
  if (node >= n) return;

  const int rs = row_start[node];
  const int dg = row_start[node + 1] - rs;

  const int half = lane >> 5;   // which edge of the pair
  const int sub  = lane & 31;   // dim-pair index (dims 2sub, 2sub+1)

  float wpart = 0.f;
  float acc0 = 0.f, acc1 = 0.f;

  for (int b = 0; b < dg; b += 64) {
    int i = b + lane;
    unsigned pk = (i < dg) ? csr4[rs + i] : 0u;   // w bits 0 -> w = 0
    wpart += h2f_bits((unsigned short)(pk >> 16));
    const int cnt = (dg - b < 64) ? (dg - b) : 64;

    int j = 0;
    for (; j + 8 <= cnt; j += 8) {
#pragma unroll
      for (int q = 0; q < 4; ++q) {
        int e = j + 2 * q + half;
        unsigned pe = __shfl(pk, e, 64);
        float we = h2f_bits((unsigned short)(pe >> 16));
        unsigned se = pe & 0xFFFFu;
        unsigned hb = h2[(size_t)se * 32 + sub];
        float f0 = __uint_as_float((hb & 0xFFFFu) << 16);
        float f1 = __uint_as_float(hb & 0xFFFF0000u);
        acc0 = fmaf(we, f0, acc0);
        acc1 = fmaf(we, f1, acc1);
      }
    }
    for (; j < cnt; j += 2) {
      int e = j + half;
      bool val = e < cnt;
      unsigned pe = __shfl(pk, val ? e : 0, 64);
      float we = val ? h2f_bits((unsigned short)(pe >> 16)) : 0.f;
      unsigned se = val ? (pe & 0xFFFFu) : 0u;
      unsigned hb = h2[(size_t)se * 32 + sub];
      float f0 = __uint_as_float((hb & 0xFFFFu) << 16);
      float f1 = __uint_as_float(hb & 0xFFFF0000u);
      acc0 = fmaf(we, f0, acc0);
      acc1 = fmaf(we, f1, acc1);
    }
  }

  // combine the two edge-halves; reduce w-sum over all 64 lanes
  acc0 += __shfl_xor(acc0, 32, 64);
  acc1 += __shfl_xor(acc1, 32, 64);
  float wsum = wpart;
#pragma unroll
  for (int o = 32; o; o >>= 1) wsum += __shfl_xor(wsum, o, 64);
  const float inv = 1.f / wsum;

  float2 bb = ((const float2*)bias)[sub];
  float2 ww = ((const float2*)W_lin)[sub];
  float v0 = fmaxf(acc0 * inv + bb.x, 0.f);
  float v1 = fmaxf(acc1 * inv + bb.y, 0.f);
  float z = v0 * ww.x + v1 * ww.y;
#pragma unroll
  for (int o = 16; o; o >>= 1) z += __shfl_xor(z, o, 64);  // sum lanes 0..31
  if (lane == 0)
    y[node] = 1.f / (1.f + expf(-(z + b_lin[0])));
}

// ---------------------------------------------------------------------------

extern "C" void kernel_launch(void* const* d_in, const int* in_sizes, int n_in,
                              void* d_out, int out_size, void* d_ws, size_t ws_size,
                              hipStream_t stream)
{
  const float* x     = (const float*)d_in[0];
  const int*   ei    = (const int*)d_in[1];
  const float* W     = (const float*)d_in[2];
  const float* att_s = (const float*)d_in[3];
  const float* att_d = (const float*)d_in[4];
  const float* bias  = (const float*)d_in[5];
  const float* W_lin = (const float*)d_in[6];
  const float* b_lin = (const float*)d_in[7];
  float* y = (float*)d_out;

  const int n = in_sizes[0] / IND;
  const int E = in_sizes[1] / 2;
  const long long E2 = (long long)E + n;
  const int nblk  = (int)((E2 + EPB - 1) / EPB);         // sort blocks (208)
  const int nbuck = (n + (1 << CBSHIFT) - 1) >> CBSHIFT; // coarse buckets (196)
  const int cntN  = nbuck * nblk;                        // cnt matrix (40768)
  const int nbs   = (cntN + 255) / 256;                  // scan blocks (160)

  // Workspace (~14 MB). Every buffer fully written before read, every call.
  char* ws = (char*)d_ws;
  unsigned short* h = (unsigned short*)ws; ws += (size_t)n * HID * sizeof(unsigned short);
  float*    a_src  = (float*)ws;    ws += (size_t)n * sizeof(float);
  float*    a_dst  = (float*)ws;    ws += (size_t)n * sizeof(float);
  int*      row_st = (int*)ws;      ws += (size_t)(n + 1) * sizeof(int);
  int*      cnt    = (int*)ws;      ws += (size_t)cntN * sizeof(int);
  int*      cntS   = (int*)ws;      ws += (size_t)cntN * sizeof(int);
  int*      bsums  = (int*)ws;      ws += (size_t)1024 * sizeof(int);
  unsigned* tmp    = (unsigned*)ws; ws += (size_t)E2 * sizeof(unsigned);
  unsigned* csr4   = (unsigned*)ws; ws += (size_t)E2 * sizeof(unsigned);

  k_cnt<<<nblk, 256, 0, stream>>>(ei, cnt, E, E2, nblk, nbuck);
  k_scan_a<<<nbs, 256, 0, stream>>>(cnt, bsums, cntN);
  k_scan_b<<<1, 1024, 0, stream>>>(bsums, nbs);
  k_scan_c<<<nbs, 256, 0, stream>>>(cnt, bsums, cntS, cntN);

  k_proj<<<(n + 63) / 64, 256, 0, stream>>>(x, W, att_s, att_d, h, a_src, a_dst, n);

  k_sortout<<<nblk, 256, 0, stream>>>(ei, cntS, tmp, E, E2, nblk, nbuck);
  k_csr<<<nbuck, 256, 0, stream>>>(tmp, cntS, a_src, a_dst, row_st, csr4,
                                   (int)E2, n, nblk, nbuck);

  k_gather_final<<<(n + 3) / 4, 256, 0, stream>>>(
      row_st, csr4, (const unsigned*)h, bias, W_lin, b_lin, y, n);
}

// Round 10
// 173.488 us; speedup vs baseline: 3.6093x; 3.6093x over previous
//
#include <hip/hip_runtime.h>
#include <hip/hip_bf16.h>
#include <hip/hip_fp16.h>
#include <cstdint>

#define IND 128
#define HID 64
#define NEG_SLOPE 0.2f
#define LSTRIDE 132   // 128 + 4: 16B-aligned rows, proven conflict-light
#define EPB 4096      // edges per sort block
#define CBSHIFT 8     // coarse bucket = 256 consecutive dst nodes

__device__ __forceinline__ unsigned short f2bf_bits(float f) {
  __hip_bfloat16 b = __float2bfloat16(f);
  return *reinterpret_cast<unsigned short*>(&b);
}
__device__ __forceinline__ unsigned short f2h_bits(float f) {
  __half h = __float2half(f);
  return *reinterpret_cast<unsigned short*>(&h);
}
__device__ __forceinline__ float h2f_bits(unsigned short u) {
  __half_raw r; r.x = u;
  return __half2float(__half(r));
}

// ---------------------------------------------------------------------------
// K1: h(bf16) = x @ W.T ; a_src/a_dst fp32. ROUND-4 STRUCTURE (VGPR 176,
// no spills): full K staged once, 64x64 tile, microtile 4x4.
// Only change: h stored as bf16 ushort4.
// ---------------------------------------------------------------------------
__global__ __launch_bounds__(256) void k_proj(
    const float* __restrict__ x, const float* __restrict__ W,
    const float* __restrict__ att_s, const float* __restrict__ att_d,
    unsigned short* __restrict__ h, float* __restrict__ a_src,
    float* __restrict__ a_dst, int n)
{
  __shared__ float xs[64 * LSTRIDE];
  __shared__ float wt[64 * LSTRIDE];
  __shared__ float sa_l[64], sd_l[64];

  const int tid = threadIdx.x;
  const int nodeBase = blockIdx.x * 64;

  if (tid < 64) { sa_l[tid] = 0.f; sd_l[tid] = 0.f; }

#pragma unroll
  for (int it = 0; it < 8; ++it) {
    int fi = (it * 256 + tid) * 4;
    int hid = fi >> 7, k = fi & 127;
    float4 v = *(const float4*)(W + fi);
    *(float4*)&wt[hid * LSTRIDE + k] = v;
  }
#pragma unroll
  for (int it = 0; it < 8; ++it) {
    int fi = (it * 256 + tid) * 4;
    int nl = fi >> 7, k = fi & 127;
    int node = nodeBase + nl; if (node >= n) node = n - 1;
    float4 v = *(const float4*)(x + (size_t)node * IND + k);
    *(float4*)&xs[nl * LSTRIDE + k] = v;
  }
  __syncthreads();

  const int ng = tid & 15;
  const int hg = tid >> 4;
  const float* xrow0 = &xs[(4 * ng) * LSTRIDE];
  const float* wrow0 = &wt[(4 * hg) * LSTRIDE];

  float acc[4][4];
#pragma unroll
  for (int j = 0; j < 4; ++j)
#pragma unroll
    for (int i = 0; i < 4; ++i) acc[j][i] = 0.f;

  for (int k = 0; k < IND; k += 4) {
    float4 a[4], b[4];
#pragma unroll
    for (int j = 0; j < 4; ++j) a[j] = *(const float4*)(xrow0 + j * LSTRIDE + k);
#pragma unroll
    for (int i = 0; i < 4; ++i) b[i] = *(const float4*)(wrow0 + i * LSTRIDE + k);
#pragma unroll
    for (int j = 0; j < 4; ++j)
#pragma unroll
      for (int i = 0; i < 4; ++i) {
        acc[j][i] = fmaf(a[j].x, b[i].x, acc[j][i]);
        acc[j][i] = fmaf(a[j].y, b[i].y, acc[j][i]);
        acc[j][i] = fmaf(a[j].z, b[i].z, acc[j][i]);
        acc[j][i] = fmaf(a[j].w, b[i].w, acc[j][i]);
      }
  }

  // h tile store (bf16): 4 dims = 8B per (thread, node)
#pragma unroll
  for (int j = 0; j < 4; ++j) {
    int node = nodeBase + 4 * ng + j;
    if (node < n) {
      ushort4 hv;
      hv.x = f2bf_bits(acc[j][0]);
      hv.y = f2bf_bits(acc[j][1]);
      hv.z = f2bf_bits(acc[j][2]);
      hv.w = f2bf_bits(acc[j][3]);
      *(ushort4*)(h + (size_t)node * HID + 4 * hg) = hv;
    }
  }

  float4 as4 = *(const float4*)(att_s + 4 * hg);
  float4 ad4 = *(const float4*)(att_d + 4 * hg);
#pragma unroll
  for (int j = 0; j < 4; ++j) {
    float ps = acc[j][0]*as4.x + acc[j][1]*as4.y + acc[j][2]*as4.z + acc[j][3]*as4.w;
    float pd = acc[j][0]*ad4.x + acc[j][1]*ad4.y + acc[j][2]*ad4.z + acc[j][3]*ad4.w;
    ps += __shfl_xor(ps, 16, 64); ps += __shfl_xor(ps, 32, 64);
    pd += __shfl_xor(pd, 16, 64); pd += __shfl_xor(pd, 32, 64);
    if ((tid & 63) < 16) {
      atomicAdd(&sa_l[4 * ng + j], ps);
      atomicAdd(&sd_l[4 * ng + j], pd);
    }
  }
  __syncthreads();
  if (tid < 64) {
    int node = nodeBase + tid;
    if (node < n) { a_src[node] = sa_l[tid]; a_dst[node] = sd_l[tid]; }
  }
}

// ---------------------------------------------------------------------------
// K2: per-(sort block, coarse bucket) histogram. cnt bucket-major.
// ---------------------------------------------------------------------------
__global__ __launch_bounds__(256) void k_cnt(
    const int* __restrict__ ei, int* __restrict__ cnt,
    int E, long long E2, int nblk, int nbuck)
{
  __shared__ int hist[256];
  const int tid = threadIdx.x;
  hist[tid] = 0;
  __syncthreads();

  const long long i0 = (long long)blockIdx.x * EPB;
  const int cntE = (int)((E2 - i0 < EPB) ? (E2 - i0) : EPB);
  for (int j = tid; j < cntE; j += 256) {
    long long idx = i0 + j;
    int d = (idx < E) ? ei[E + idx] : (int)(idx - E);
    atomicAdd(&hist[d >> CBSHIFT], 1);
  }
  __syncthreads();
  if (tid < nbuck) cnt[tid * nblk + blockIdx.x] = hist[tid];
}

// ---------------------------------------------------------------------------
// K3a/b/c: multi-block exclusive scan of cnt[0..cntN) -> cntS.
// ---------------------------------------------------------------------------
__global__ __launch_bounds__(256) void k_scan_a(
    const int* __restrict__ vals, int* __restrict__ blockSums, int cntN)
{
  __shared__ int red[4];
  int i = blockIdx.x * 256 + threadIdx.x;
  int v = (i < cntN) ? vals[i] : 0;
#pragma unroll
  for (int o = 32; o; o >>= 1) v += __shfl_xor(v, o, 64);
  if ((threadIdx.x & 63) == 0) red[threadIdx.x >> 6] = v;
  __syncthreads();
  if (threadIdx.x == 0)
    blockSums[blockIdx.x] = red[0] + red[1] + red[2] + red[3];
}

__global__ __launch_bounds__(1024) void k_scan_b(
    int* __restrict__ blockSums, int nb)
{
  __shared__ int sums[1024];
  const int tid = threadIdx.x;
  int v = (tid < nb) ? blockSums[tid] : 0;
  sums[tid] = v;
  __syncthreads();
  for (int off = 1; off < 1024; off <<= 1) {
    int t = (tid >= off) ? sums[tid - off] : 0;
    __syncthreads();
    sums[tid] += t;
    __syncthreads();
  }
  if (tid < nb) blockSums[tid] = sums[tid] - v;
}

__global__ __launch_bounds__(256) void k_scan_c(
    const int* __restrict__ vals, const int* __restrict__ blockSums,
    int* __restrict__ out, int cntN)
{
  __shared__ int sums[256];
  const int tid = threadIdx.x;
  int i = blockIdx.x * 256 + tid;
  int v = (i < cntN) ? vals[i] : 0;
  sums[tid] = v;
  __syncthreads();
  for (int off = 1; off < 256; off <<= 1) {
    int t = (tid >= off) ? sums[tid - off] : 0;
    __syncthreads();
    sums[tid] += t;
    __syncthreads();
  }
  if (i < cntN) out[i] = sums[tid] - v + blockSums[blockIdx.x];
}

// ---------------------------------------------------------------------------
// K4: block-level counting sort of EPB edges by coarse bucket, then LINEAR
// write-out (block owns each run -> lines fill). Packed 4B: (dst<<16)|src.
// ---------------------------------------------------------------------------
__global__ __launch_bounds__(256) void k_sortout(
    const int* __restrict__ ei, const int* __restrict__ cntS,
    unsigned* __restrict__ tmp, int E, long long E2, int nblk, int nbuck)
{
  __shared__ int hist[256];
  __shared__ int sums[256];
  __shared__ int cur[256];
  __shared__ int gbase[256];
  __shared__ unsigned sorted[EPB];

  const int tid = threadIdx.x;
  hist[tid] = 0;
  __syncthreads();

  const long long i0 = (long long)blockIdx.x * EPB;

  unsigned pk[EPB / 256];
#pragma unroll
  for (int j = 0; j < EPB / 256; ++j) {
    long long idx = i0 + j * 256 + tid;
    unsigned v = 0xFFFFFFFFu;
    if (idx < E2) {
      int s, d;
      if (idx < E) { s = ei[idx]; d = ei[E + idx]; }
      else         { s = d = (int)(idx - E); }
      v = ((unsigned)d << 16) | (unsigned)s;
      atomicAdd(&hist[d >> CBSHIFT], 1);
    }
    pk[j] = v;
  }
  __syncthreads();

  sums[tid] = hist[tid];
  __syncthreads();
  for (int off = 1; off < 256; off <<= 1) {
    int t = (tid >= off) ? sums[tid - off] : 0;
    __syncthreads();
    sums[tid] += t;
    __syncthreads();
  }
  const int lstart_t = sums[tid] - hist[tid];
  cur[tid] = lstart_t;
  gbase[tid] = (tid < nbuck) ? cntS[tid * nblk + blockIdx.x] : 0;
  __syncthreads();
  hist[tid] = lstart_t;
  __syncthreads();

#pragma unroll
  for (int j = 0; j < EPB / 256; ++j) {
    unsigned v = pk[j];
    if (v != 0xFFFFFFFFu) {
      int b = v >> (16 + CBSHIFT);
      int lpos = atomicAdd(&cur[b], 1);
      sorted[lpos] = v;
    }
  }
  __syncthreads();

  const int cntE = (int)((E2 - i0 < EPB) ? (E2 - i0) : EPB);
  for (int i = tid; i < cntE; i += 256) {
    unsigned v = sorted[i];
    int b = v >> (16 + CBSHIFT);
    tmp[gbase[b] + (i - hist[b])] = v;
  }
}

// ---------------------------------------------------------------------------
// K5: per-coarse-bucket exact CSR + edge weight. Block owns the bucket's
// contiguous CSR region: LDS deg -> scan -> row_start, LDS int cursors ->
// csr4 packed {src:16, fp16(w):16} (4B/edge, block-owned dense writes).
// ---------------------------------------------------------------------------
__global__ __launch_bounds__(256) void k_csr(
    const unsigned* __restrict__ tmp, const int* __restrict__ cntS,
    const float* __restrict__ a_src, const float* __restrict__ a_dst,
    int* __restrict__ row_start, unsigned* __restrict__ csr4,
    int E2total, int n, int nblk, int nbuck)
{
  __shared__ int degl[256], sums[256], cur[256];
  __shared__ float adl[256];

  const int tid = threadIdx.x;
  const int b   = blockIdx.x;
  const int n0  = b << CBSHIFT;
  const int base = cntS[b * nblk];
  const int next = (b + 1 < nbuck) ? cntS[(b + 1) * nblk] : E2total;

  degl[tid] = 0;
  const int node = n0 + tid;
  adl[tid] = (node < n) ? a_dst[node] : 0.f;
  __syncthreads();

  for (int i = base + tid; i < next; i += 256)
    atomicAdd(&degl[(tmp[i] >> 16) - n0], 1);
  __syncthreads();

  sums[tid] = degl[tid];
  __syncthreads();
  for (int off = 1; off < 256; off <<= 1) {
    int t = (tid >= off) ? sums[tid - off] : 0;
    __syncthreads();
    sums[tid] += t;
    __syncthreads();
  }
  const int rs = base + sums[tid] - degl[tid];
  cur[tid] = rs;
  if (node < n) row_start[node] = rs;
  if (b == nbuck - 1 && tid == 0) row_start[n] = E2total;
  __syncthreads();

  for (int i = base + tid; i < next; i += 256) {
    unsigned v = tmp[i];
    int s  = (int)(v & 0xFFFFu);
    int dl = (int)(v >> 16) - n0;
    float sc = a_src[s] + adl[dl];
    sc = (sc >= 0.f) ? sc : NEG_SLOPE * sc;
    float w = expf(sc);
    int pos = atomicAdd(&cur[dl], 1);
    csr4[pos] = (unsigned)s | ((unsigned)f2h_bits(w) << 16);
  }
}

// ---------------------------------------------------------------------------
// K6: single-pass gather + epilogue. One wave per node. csr4 read once:
// w-sum accumulates in-register alongside the aggregate. Two edges per wave
// iteration: lanes 0-31 handle edge j (dims via bf16x2), lanes 32-63 edge
// j+1; halves combined with one shfl_xor(32) at the end. Register acc only.
// ---------------------------------------------------------------------------
__global__ __launch_bounds__(256) void k_gather_final(
    const int* __restrict__ row_start, const unsigned* __restrict__ csr4,
    const unsigned* __restrict__ h2, const float* __restrict__ bias,
    const float* __restrict__ W_lin, const float* __restrict__ b_lin,
    float* __restrict__ y, int n)
{
  const int lane = threadIdx.x & 63;
  const int wid  = threadIdx.x >> 6;
  const int node = blockIdx.x * 4 + wid;
  if (node >= n) return;

  const int rs = row_start[node];
  const int dg = row_start[node + 1] - rs;

  const int half = lane >> 5;   // which edge of the pair
  const int sub  = lane & 31;   // dim-pair index (dims 2sub, 2sub+1)

  float wpart = 0.f;
  float acc0 = 0.f, acc1 = 0.f;

  for (int b = 0; b < dg; b += 64) {
    int i = b + lane;
    unsigned pk = (i < dg) ? csr4[rs + i] : 0u;   // w bits 0 -> w = 0
    wpart += h2f_bits((unsigned short)(pk >> 16));
    const int cnt = (dg - b < 64) ? (dg - b) : 64;

    int j = 0;
    for (; j + 8 <= cnt; j += 8) {
#pragma unroll
      for (int q = 0; q < 4; ++q) {
        int e = j + 2 * q + half;
        unsigned pe = __shfl(pk, e, 64);
        float we = h2f_bits((unsigned short)(pe >> 16));
        unsigned se = pe & 0xFFFFu;
        unsigned hb = h2[(size_t)se * 32 + sub];
        float f0 = __uint_as_float((hb & 0xFFFFu) << 16);
        float f1 = __uint_as_float(hb & 0xFFFF0000u);
        acc0 = fmaf(we, f0, acc0);
        acc1 = fmaf(we, f1, acc1);
      }
    }
    for (; j < cnt; j += 2) {
      int e = j + half;
      bool val = e < cnt;
      unsigned pe = __shfl(pk, val ? e : 0, 64);
      float we = val ? h2f_bits((unsigned short)(pe >> 16)) : 0.f;
      unsigned se = val ? (pe & 0xFFFFu) : 0u;
      unsigned hb = h2[(size_t)se * 32 + sub];
      float f0 = __uint_as_float((hb & 0xFFFFu) << 16);
      float f1 = __uint_as_float(hb & 0xFFFF0000u);
      acc0 = fmaf(we, f0, acc0);
      acc1 = fmaf(we, f1, acc1);
    }
  }

  acc0 += __shfl_xor(acc0, 32, 64);
  acc1 += __shfl_xor(acc1, 32, 64);
  float wsum = wpart;
#pragma unroll
  for (int o = 32; o; o >>= 1) wsum += __shfl_xor(wsum, o, 64);
  const float inv = 1.f / wsum;

  float2 bb = ((const float2*)bias)[sub];
  float2 ww = ((const float2*)W_lin)[sub];
  float v0 = fmaxf(acc0 * inv + bb.x, 0.f);
  float v1 = fmaxf(acc1 * inv + bb.y, 0.f);
  float z = v0 * ww.x + v1 * ww.y;
#pragma unroll
  for (int o = 16; o; o >>= 1) z += __shfl_xor(z, o, 64);
  if (lane == 0)
    y[node] = 1.f / (1.f + expf(-(z + b_lin[0])));
}

// ---------------------------------------------------------------------------

extern "C" void kernel_launch(void* const* d_in, const int* in_sizes, int n_in,
                              void* d_out, int out_size, void* d_ws, size_t ws_size,
                              hipStream_t stream)
{
  const float* x     = (const float*)d_in[0];
  const int*   ei    = (const int*)d_in[1];
  const float* W     = (const float*)d_in[2];
  const float* att_s = (const float*)d_in[3];
  const float* att_d = (const float*)d_in[4];
  const float* bias  = (const float*)d_in[5];
  const float* W_lin = (const float*)d_in[6];
  const float* b_lin = (const float*)d_in[7];
  float* y = (float*)d_out;

  const int n = in_sizes[0] / IND;
  const int E = in_sizes[1] / 2;
  const long long E2 = (long long)E + n;
  const int nblk  = (int)((E2 + EPB - 1) / EPB);         // sort blocks (208)
  const int nbuck = (n + (1 << CBSHIFT) - 1) >> CBSHIFT; // coarse buckets (196)
  const int cntN  = nbuck * nblk;                        // cnt matrix (40768)
  const int nbs   = (cntN + 255) / 256;                  // scan blocks (160)

  // Workspace (~14 MB). Every buffer fully written before read, every call.
  char* ws = (char*)d_ws;
  unsigned short* h = (unsigned short*)ws; ws += (size_t)n * HID * sizeof(unsigned short);
  float*    a_src  = (float*)ws;    ws += (size_t)n * sizeof(float);
  float*    a_dst  = (float*)ws;    ws += (size_t)n * sizeof(float);
  int*      row_st = (int*)ws;      ws += (size_t)(n + 1) * sizeof(int);
  int*      cnt    = (int*)ws;      ws += (size_t)cntN * sizeof(int);
  int*      cntS   = (int*)ws;      ws += (size_t)cntN * sizeof(int);
  int*      bsums  = (int*)ws;      ws += (size_t)1024 * sizeof(int);
  unsigned* tmp    = (unsigned*)ws; ws += (size_t)E2 * sizeof(unsigned);
  unsigned* csr4   = (unsigned*)ws; ws += (size_t)E2 * sizeof(unsigned);

  k_cnt<<<nblk, 256, 0, stream>>>(ei, cnt, E, E2, nblk, nbuck);
  k_scan_a<<<nbs, 256, 0, stream>>>(cnt, bsums, cntN);
  k_scan_b<<<1, 1024, 0, stream>>>(bsums, nbs);
  k_scan_c<<<nbs, 256, 0, stream>>>(cnt, bsums, cntS, cntN);

  k_proj<<<(n + 63) / 64, 256, 0, stream>>>(x, W, att_s, att_d, h, a_src, a_dst, n);

  k_sortout<<<nblk, 256, 0, stream>>>(ei, cntS, tmp, E, E2, nblk, nbuck);
  k_csr<<<nbuck, 256, 0, stream>>>(tmp, cntS, a_src, a_dst, row_st, csr4,
                                   (int)E2, n, nblk, nbuck);

  k_gather_final<<<(n + 3) / 4, 256, 0, stream>>>(
      row_st, csr4, (const unsigned*)h, bias, W_lin, b_lin, y, n);
}